// Round 2
// baseline (535.036 us; speedup 1.0000x reference)
//
#include <hip/hip_runtime.h>
#include <math.h>

#define BB 32
#define DD 64
#define LL 8192
#define KK 512
#define NN (BB*LL)                 // 262144 rows

#define OUT0_SZ  (BB*DD*LL)        // 16777216
#define LOSS_OFF (OUT0_SZ)
#define PERP_OFF (OUT0_SZ + 1)
#define W_OFF    (OUT0_SZ + 2)
#define IDX_OFF  (W_OFF + KK*DD)

// ws layout: float tvec[512] | int hist[512] | float lacc | int done
// -----------------------------------------------------------------------------
// init: t_k = ||w_k||^2 (numpy-pairwise fp32 order), zero hist/lacc/done,
// and do the weight passthrough copy (independent of main).
__global__ void vq_init(const float* __restrict__ w, float* __restrict__ tvec,
                        int* __restrict__ hist, float* __restrict__ lacc,
                        int* __restrict__ done, float* __restrict__ dout) {
#pragma clang fp contract(off)
  int gid = blockIdx.x * 256 + threadIdx.x;
  if (gid < KK) {
    const float* wr = w + gid * DD;
    float r[8];
#pragma unroll
    for (int j = 0; j < 8; j++) { float v = wr[j]; r[j] = v * v; }
#pragma unroll
    for (int blk = 8; blk < 64; blk += 8) {
#pragma unroll
      for (int j = 0; j < 8; j++) { float v = wr[blk + j]; float a = v * v; r[j] = r[j] + a; }
    }
    tvec[gid] = ((r[0] + r[1]) + (r[2] + r[3])) + ((r[4] + r[5]) + (r[6] + r[7]));
    hist[gid] = 0;
  } else if (gid == KK) {
    *lacc = 0.0f;
  } else if (gid == KK + 1) {
    *done = 0;
  }
  // weight passthrough: dout+W_OFF is 8B-aligned -> float2
  const float2* w2 = (const float2*)w;
  float2* o2 = (float2*)(dout + W_OFF);
  for (int j = gid; j < KK * DD / 2; j += 64 * 256) o2[j] = w2[j];
}

// -----------------------------------------------------------------------------
// main: 512 blocks x 256 threads, 2 rows/thread. w read from GLOBAL with
// wave-uniform addresses (L1-resident 128 KB codebook) via a VGPR ping-pong
// of 32-float halves — zero LDS in the hot loop.
__launch_bounds__(256, 2)
__global__ void vq_main(const float* __restrict__ x, const float* __restrict__ w,
                        const float* __restrict__ tvec, int* __restrict__ hist,
                        float* __restrict__ lacc, int* __restrict__ done,
                        float* __restrict__ dout) {
#pragma clang fp contract(off)
  __shared__ unsigned char flags[KK];
  __shared__ float lred[4];
  __shared__ int   ired[4];
  __shared__ int   amLast;

  const int tid = threadIdx.x;
  for (int e = tid; e < KK; e += 256) flags[e] = 0;   // barrier before use below

  const int n0 = blockIdx.x * 512 + tid;
  const int n1 = n0 + 256;
  const int b0 = n0 >> 13, l0 = n0 & 8191;
  const int b1 = n1 >> 13, l1 = n1 & 8191;
  const float* p0 = x + (size_t)b0 * DD * LL + l0;
  const float* p1 = x + (size_t)b1 * DD * LL + l1;

  float x0[64], x1[64];
#pragma unroll
  for (int i = 0; i < 64; i++) { x0[i] = p0[(size_t)i * LL]; x1[i] = p1[(size_t)i * LL]; }

  // s = ||x||^2 (uniform shift across k; order kept identical to R1)
  float s0, s1;
  {
    float r0[8], r1[8];
#pragma unroll
    for (int j = 0; j < 8; j++) { r0[j] = x0[j] * x0[j]; r1[j] = x1[j] * x1[j]; }
#pragma unroll
    for (int blk = 8; blk < 64; blk += 8) {
#pragma unroll
      for (int j = 0; j < 8; j++) {
        float a0 = x0[blk + j] * x0[blk + j]; r0[j] = r0[j] + a0;
        float a1 = x1[blk + j] * x1[blk + j]; r1[j] = r1[j] + a1;
      }
    }
    s0 = ((r0[0] + r0[1]) + (r0[2] + r0[3])) + ((r0[4] + r0[5]) + (r0[6] + r0[7]));
    s1 = ((r1[0] + r1[1]) + (r1[2] + r1[3])) + ((r1[4] + r1[5]) + (r1[6] + r1[7]));
  }

  const float4* w4 = (const float4*)w;   // code c = float4s [c*16, c*16+16)
  float4 A[8], B[8];
#pragma unroll
  for (int q = 0; q < 8; q++) A[q] = w4[q];          // code 0, half 0

  float dmin0 = INFINITY, dmin1 = INFINITY;
  int   k0 = 0, k1 = 0;

  for (int c = 0; c < KK; c++) {
    float tc = tvec[c];
    float g0 = 0.0f, g1 = 0.0f;
    // prefetch half 1 of this code
#pragma unroll
    for (int q = 0; q < 8; q++) B[q] = w4[c * 16 + 8 + q];
    // consume half 0 (k = 0..31), fmaf chain k-ascending — bit-identical to R1
#pragma unroll
    for (int q = 0; q < 8; q++) {
      float4 ww = A[q];
      g0 = fmaf(x0[4*q+0], ww.x, g0); g0 = fmaf(x0[4*q+1], ww.y, g0);
      g0 = fmaf(x0[4*q+2], ww.z, g0); g0 = fmaf(x0[4*q+3], ww.w, g0);
      g1 = fmaf(x1[4*q+0], ww.x, g1); g1 = fmaf(x1[4*q+1], ww.y, g1);
      g1 = fmaf(x1[4*q+2], ww.z, g1); g1 = fmaf(x1[4*q+3], ww.w, g1);
    }
    // prefetch half 0 of next code
    int cn = (c + 1 < KK) ? c + 1 : c;
#pragma unroll
    for (int q = 0; q < 8; q++) A[q] = w4[cn * 16 + q];
    // consume half 1 (k = 32..63)
#pragma unroll
    for (int q = 0; q < 8; q++) {
      float4 ww = B[q];
      g0 = fmaf(x0[32+4*q+0], ww.x, g0); g0 = fmaf(x0[32+4*q+1], ww.y, g0);
      g0 = fmaf(x0[32+4*q+2], ww.z, g0); g0 = fmaf(x0[32+4*q+3], ww.w, g0);
      g1 = fmaf(x1[32+4*q+0], ww.x, g1); g1 = fmaf(x1[32+4*q+1], ww.y, g1);
      g1 = fmaf(x1[32+4*q+2], ww.z, g1); g1 = fmaf(x1[32+4*q+3], ww.w, g1);
    }
    float u0 = s0 + tc;                 // fl32(s + t_k), matches np broadcast
    float u1 = s1 + tc;
    float d0 = fmaf(-2.0f, g0, u0);     // fl32(u - 2g), 2g exact
    float d1 = fmaf(-2.0f, g1, u1);
    if (d0 < dmin0) { dmin0 = d0; k0 = c; }   // strict <: first index on tie
    if (d1 < dmin1) { dmin1 = d1; k1 = c; }
  }

  // epilogue: quantized output (transposed), loss partial, idx
  float ls = 0.0f;
  {
    float* o0 = dout + (size_t)b0 * DD * LL + l0;
    const float4* wr = (const float4*)(w + k0 * DD);
#pragma unroll
    for (int i = 0; i < 16; i++) {
      float4 v = wr[i];
      o0[(size_t)(4*i+0) * LL] = v.x; o0[(size_t)(4*i+1) * LL] = v.y;
      o0[(size_t)(4*i+2) * LL] = v.z; o0[(size_t)(4*i+3) * LL] = v.w;
      float df;
      df = v.x - x0[4*i+0]; ls = fmaf(df, df, ls);
      df = v.y - x0[4*i+1]; ls = fmaf(df, df, ls);
      df = v.z - x0[4*i+2]; ls = fmaf(df, df, ls);
      df = v.w - x0[4*i+3]; ls = fmaf(df, df, ls);
    }
  }
  {
    float* o1 = dout + (size_t)b1 * DD * LL + l1;
    const float4* wr = (const float4*)(w + k1 * DD);
#pragma unroll
    for (int i = 0; i < 16; i++) {
      float4 v = wr[i];
      o1[(size_t)(4*i+0) * LL] = v.x; o1[(size_t)(4*i+1) * LL] = v.y;
      o1[(size_t)(4*i+2) * LL] = v.z; o1[(size_t)(4*i+3) * LL] = v.w;
      float df;
      df = v.x - x1[4*i+0]; ls = fmaf(df, df, ls);
      df = v.y - x1[4*i+1]; ls = fmaf(df, df, ls);
      df = v.z - x1[4*i+2]; ls = fmaf(df, df, ls);
      df = v.w - x1[4*i+3]; ls = fmaf(df, df, ls);
    }
  }
  dout[IDX_OFF + n0] = (float)k0;
  dout[IDX_OFF + n1] = (float)k1;

  // block loss reduction -> one atomic per block
#pragma unroll
  for (int o = 32; o > 0; o >>= 1) ls += __shfl_down(ls, o);
  if ((tid & 63) == 0) lred[tid >> 6] = ls;
  __syncthreads();                       // covers flags zeroing + lred
  flags[k0] = 1; flags[k1] = 1;
  if (tid == 0) atomicAdd(lacc, (lred[0] + lred[1]) + (lred[2] + lred[3]));
  __syncthreads();
  for (int e = tid; e < KK; e += 256)
    if (flags[e]) atomicOr(&hist[e], 1);

  // last-done block finalizes loss + perplexity (replaces vq_final launch)
  __threadfence();
  __syncthreads();
  if (tid == 0) {
    int old = __hip_atomic_fetch_add(done, 1, __ATOMIC_ACQ_REL, __HIP_MEMORY_SCOPE_AGENT);
    amLast = (old == (int)gridDim.x - 1);
  }
  __syncthreads();
  if (amLast) {
    __threadfence();
    int v = (__hip_atomic_load(&hist[tid],       __ATOMIC_RELAXED, __HIP_MEMORY_SCOPE_AGENT) != 0)
          + (__hip_atomic_load(&hist[tid + 256], __ATOMIC_RELAXED, __HIP_MEMORY_SCOPE_AGENT) != 0);
#pragma unroll
    for (int o = 32; o > 0; o >>= 1) v += __shfl_down(v, o);
    if ((tid & 63) == 0) ired[tid >> 6] = v;
    __syncthreads();
    if (tid == 0) {
      float m = __hip_atomic_load(lacc, __ATOMIC_RELAXED, __HIP_MEMORY_SCOPE_AGENT)
                / 16777216.0f;
      dout[LOSS_OFF] = m + 0.1f * m;     // q + 0.1*e with q==e numerically
      dout[PERP_OFF] = (float)(ired[0] + ired[1] + ired[2] + ired[3]);
    }
  }
}

extern "C" void kernel_launch(void* const* d_in, const int* in_sizes, int n_in,
                              void* d_out, int out_size, void* d_ws, size_t ws_size,
                              hipStream_t stream) {
  const float* x = (const float*)d_in[0];
  const float* w = (const float*)d_in[1];
  float* dout = (float*)d_out;
  float* tvec = (float*)d_ws;
  int*   hist = (int*)d_ws + 512;
  float* lacc = (float*)d_ws + 1024;
  int*   done = (int*)d_ws + 1025;

  vq_init<<<64, 256, 0, stream>>>(w, tvec, hist, lacc, done, dout);
  vq_main<<<NN / 512, 256, 0, stream>>>(x, w, tvec, hist, lacc, done, dout);
}

// Round 4
// 503.473 us; speedup vs baseline: 1.0627x; 1.0627x over previous
//
#include <hip/hip_runtime.h>
#include <math.h>

#define BB 32
#define DD 64
#define LL 8192
#define KK 512
#define NN (BB*LL)                 // 262144 rows

#define OUT0_SZ  (BB*DD*LL)        // 16777216
#define LOSS_OFF (OUT0_SZ)
#define PERP_OFF (OUT0_SZ + 1)
#define W_OFF    (OUT0_SZ + 2)
#define IDX_OFF  (W_OFF + KK*DD)

typedef __attribute__((ext_vector_type(16))) float sf16;
#define AS4 __attribute__((address_space(4)))

// ws layout: int hist[512] | float lacc | int done
// -----------------------------------------------------------------------------
// init: zero hist/lacc/done, weight passthrough (proven R2 structure, no tvec)
__global__ void vq_init(const float* __restrict__ w, int* __restrict__ hist,
                        float* __restrict__ lacc, int* __restrict__ done,
                        float* __restrict__ dout) {
  int gid = blockIdx.x * 256 + threadIdx.x;
  if (gid < KK) hist[gid] = 0;
  else if (gid == KK) *lacc = 0.0f;
  else if (gid == KK + 1) *done = 0;
  // dout+W_OFF is 8B-aligned -> float2 copies; 16384 threads, 1 each
  const float2* w2 = (const float2*)w;
  float2* o2 = (float2*)(dout + W_OFF);
  for (int j = gid; j < KK * DD / 2; j += 64 * 256) o2[j] = w2[j];
}

// -----------------------------------------------------------------------------
// main: 1024 blocks x 256 threads, 1 row/thread, 4 waves/SIMD.
// Codebook streamed through the scalar pipe: addrspace(4) + uniform address
// selects s_load_dwordx16; v_fma_f32 consumes w as its one SGPR operand.
__launch_bounds__(256, 4)
__global__ void vq_main(const float* __restrict__ x, const float* __restrict__ w,
                        int* __restrict__ hist, float* __restrict__ lacc,
                        int* __restrict__ done, float* __restrict__ dout) {
#pragma clang fp contract(off)
  __shared__ float tt[KK];            // ||w_k||^2, numpy-pairwise order
  __shared__ unsigned char flags[KK];
  __shared__ float lred[4];
  __shared__ int   ired[4];
  __shared__ int   amLast;

  const int tid = threadIdx.x;

  // per-block t_k (2 codes/thread) + flags zeroing; exact pairwise fp32 order
  for (int kk = tid; kk < KK; kk += 256) {
    const float* wr = w + kk * DD;
    float r[8];
#pragma unroll
    for (int j = 0; j < 8; j++) { float v = wr[j]; r[j] = v * v; }
#pragma unroll
    for (int blk = 8; blk < 64; blk += 8) {
#pragma unroll
      for (int j = 0; j < 8; j++) { float v = wr[blk + j]; float a = v * v; r[j] = r[j] + a; }
    }
    tt[kk] = ((r[0] + r[1]) + (r[2] + r[3])) + ((r[4] + r[5]) + (r[6] + r[7]));
    flags[kk] = 0;
  }

  const int n0 = blockIdx.x * 256 + tid;
  const int b0 = n0 >> 13, l0 = n0 & 8191;
  const float* p0 = x + (size_t)b0 * DD * LL + l0;

  float x0[64];
#pragma unroll
  for (int i = 0; i < 64; i++) x0[i] = p0[(size_t)i * LL];

  // s = ||x||^2 (uniform shift across k; order identical to R1)
  float s0;
  {
    float r0[8];
#pragma unroll
    for (int j = 0; j < 8; j++) r0[j] = x0[j] * x0[j];
#pragma unroll
    for (int blk = 8; blk < 64; blk += 8) {
#pragma unroll
      for (int j = 0; j < 8; j++) { float a0 = x0[blk + j] * x0[blk + j]; r0[j] = r0[j] + a0; }
    }
    s0 = ((r0[0] + r0[1]) + (r0[2] + r0[3])) + ((r0[4] + r0[5]) + (r0[6] + r0[7]));
  }

  __syncthreads();   // tt/flags ready

  // constant-addrspace view of the codebook (uniform loads -> s_load_dwordx16)
  const AS4 sf16* wc = (const AS4 sf16*)(unsigned long long)(const void*)w;

  float dmin0 = INFINITY;
  int   k0 = 0;

  for (int c = 0; c < KK; c++) {
    float tc = tt[c];
    sf16 A0 = wc[c * 4 + 0];
    sf16 A1 = wc[c * 4 + 1];
    float g0 = 0.0f;
    // fmaf chain k-ascending — bit-identical to R1
#pragma unroll
    for (int j = 0; j < 16; j++) g0 = fmaf(x0[j], A0[j], g0);
#pragma unroll
    for (int j = 0; j < 16; j++) g0 = fmaf(x0[16 + j], A1[j], g0);
    sf16 B0 = wc[c * 4 + 2];
    sf16 B1 = wc[c * 4 + 3];
#pragma unroll
    for (int j = 0; j < 16; j++) g0 = fmaf(x0[32 + j], B0[j], g0);
#pragma unroll
    for (int j = 0; j < 16; j++) g0 = fmaf(x0[48 + j], B1[j], g0);
    float u0 = s0 + tc;                 // fl32(s + t_k), matches np broadcast
    float d0 = fmaf(-2.0f, g0, u0);     // fl32(u - 2g), 2g exact
    if (d0 < dmin0) { dmin0 = d0; k0 = c; }   // strict <: first index on tie
  }

  // epilogue: quantized output (transposed), loss partial, idx
  float ls = 0.0f;
  {
    float* o0 = dout + (size_t)b0 * DD * LL + l0;
    const float4* wr = (const float4*)(w + k0 * DD);
#pragma unroll
    for (int i = 0; i < 16; i++) {
      float4 v = wr[i];
      o0[(size_t)(4*i+0) * LL] = v.x; o0[(size_t)(4*i+1) * LL] = v.y;
      o0[(size_t)(4*i+2) * LL] = v.z; o0[(size_t)(4*i+3) * LL] = v.w;
      float df;
      df = v.x - x0[4*i+0]; ls = fmaf(df, df, ls);
      df = v.y - x0[4*i+1]; ls = fmaf(df, df, ls);
      df = v.z - x0[4*i+2]; ls = fmaf(df, df, ls);
      df = v.w - x0[4*i+3]; ls = fmaf(df, df, ls);
    }
  }
  dout[IDX_OFF + n0] = (float)k0;

  // block loss reduction -> one atomic per block
#pragma unroll
  for (int o = 32; o > 0; o >>= 1) ls += __shfl_down(ls, o);
  if ((tid & 63) == 0) lred[tid >> 6] = ls;
  __syncthreads();
  flags[k0] = 1;
  if (tid == 0) atomicAdd(lacc, (lred[0] + lred[1]) + (lred[2] + lred[3]));
  __syncthreads();
  for (int e = tid; e < KK; e += 256)
    if (flags[e]) atomicOr(&hist[e], 1);

  // last-done block finalizes loss + perplexity
  __threadfence();
  __syncthreads();
  if (tid == 0) {
    int old = __hip_atomic_fetch_add(done, 1, __ATOMIC_ACQ_REL, __HIP_MEMORY_SCOPE_AGENT);
    amLast = (old == (int)gridDim.x - 1);
  }
  __syncthreads();
  if (amLast) {
    __threadfence();
    int v = (__hip_atomic_load(&hist[tid],       __ATOMIC_RELAXED, __HIP_MEMORY_SCOPE_AGENT) != 0)
          + (__hip_atomic_load(&hist[tid + 256], __ATOMIC_RELAXED, __HIP_MEMORY_SCOPE_AGENT) != 0);
#pragma unroll
    for (int o = 32; o > 0; o >>= 1) v += __shfl_down(v, o);
    if ((tid & 63) == 0) ired[tid >> 6] = v;
    __syncthreads();
    if (tid == 0) {
      float m = __hip_atomic_load(lacc, __ATOMIC_RELAXED, __HIP_MEMORY_SCOPE_AGENT)
                / 16777216.0f;
      dout[LOSS_OFF] = m + 0.1f * m;     // q + 0.1*e with q==e numerically
      dout[PERP_OFF] = (float)(ired[0] + ired[1] + ired[2] + ired[3]);
    }
  }
}

extern "C" void kernel_launch(void* const* d_in, const int* in_sizes, int n_in,
                              void* d_out, int out_size, void* d_ws, size_t ws_size,
                              hipStream_t stream) {
  const float* x = (const float*)d_in[0];
  const float* w = (const float*)d_in[1];
  float* dout = (float*)d_out;
  int*   hist = (int*)d_ws;
  float* lacc = (float*)((int*)d_ws + 512);
  int*   done = (int*)d_ws + 513;

  vq_init<<<64, 256, 0, stream>>>(w, hist, lacc, done, dout);
  vq_main<<<NN / 256, 256, 0, stream>>>(x, w, hist, lacc, done, dout);
}

// Round 5
// 502.806 us; speedup vs baseline: 1.0641x; 1.0013x over previous
//
#include <hip/hip_runtime.h>
#include <math.h>

#define BB 32
#define DD 64
#define LL 8192
#define KK 512
#define NN (BB*LL)                 // 262144 rows

#define OUT0_SZ  (BB*DD*LL)        // 16777216
#define LOSS_OFF (OUT0_SZ)
#define PERP_OFF (OUT0_SZ + 1)
#define W_OFF    (OUT0_SZ + 2)
#define IDX_OFF  (W_OFF + KK*DD)

typedef __attribute__((ext_vector_type(16))) float sf16;
#define AS4 __attribute__((address_space(4)))

// ws layout: int hist[512] | float lacc | int done
// -----------------------------------------------------------------------------
__global__ void vq_init(const float* __restrict__ w, int* __restrict__ hist,
                        float* __restrict__ lacc, int* __restrict__ done,
                        float* __restrict__ dout) {
  int gid = blockIdx.x * 256 + threadIdx.x;
  if (gid < KK) hist[gid] = 0;
  else if (gid == KK) *lacc = 0.0f;
  else if (gid == KK + 1) *done = 0;
  // weight passthrough: dout+W_OFF is 8B-aligned -> float2
  const float2* w2 = (const float2*)w;
  float2* o2 = (float2*)(dout + W_OFF);
  for (int j = gid; j < KK * DD / 2; j += 64 * 256) o2[j] = w2[j];
}

// -----------------------------------------------------------------------------
// main: 1024 blocks x 256 threads, 1 row/thread. Codebook through the scalar
// pipe (addrspace(4) -> s_load_dwordx16, consumed as the SGPR operand of
// v_fma_f32). waves_per_eu(4,4) PINS occupancy so the allocator keeps the
// 64-float x row in VGPRs instead of spilling to chase 8 waves/EU (R4: 48
// VGPRs = spilled row = 445us).
__attribute__((amdgpu_waves_per_eu(4, 4)))
__launch_bounds__(256)
__global__ void vq_main(const float* __restrict__ x, const float* __restrict__ w,
                        int* __restrict__ hist, float* __restrict__ lacc,
                        int* __restrict__ done, float* __restrict__ dout) {
#pragma clang fp contract(off)
  __shared__ float tt[KK];            // ||w_k||^2, numpy-pairwise order
  __shared__ unsigned char flags[KK];
  __shared__ float lred[4];
  __shared__ int   ired[4];
  __shared__ int   amLast;

  const int tid = threadIdx.x;

  // per-block t_k (2 codes/thread) + flags zeroing; exact pairwise fp32 order
  for (int kk = tid; kk < KK; kk += 256) {
    const float* wr = w + kk * DD;
    float r[8];
#pragma unroll
    for (int j = 0; j < 8; j++) { float v = wr[j]; r[j] = v * v; }
#pragma unroll
    for (int blk = 8; blk < 64; blk += 8) {
#pragma unroll
      for (int j = 0; j < 8; j++) { float v = wr[blk + j]; float a = v * v; r[j] = r[j] + a; }
    }
    tt[kk] = ((r[0] + r[1]) + (r[2] + r[3])) + ((r[4] + r[5]) + (r[6] + r[7]));
    flags[kk] = 0;
  }

  const int n0 = blockIdx.x * 256 + tid;
  const int b0 = n0 >> 13, l0 = n0 & 8191;
  const float* p0 = x + (size_t)b0 * DD * LL + l0;

  float x0[64];
#pragma unroll
  for (int i = 0; i < 64; i++) x0[i] = p0[(size_t)i * LL];

  // s = ||x||^2 (uniform shift across k; order identical to R1)
  float s0;
  {
    float r0[8];
#pragma unroll
    for (int j = 0; j < 8; j++) r0[j] = x0[j] * x0[j];
#pragma unroll
    for (int blk = 8; blk < 64; blk += 8) {
#pragma unroll
      for (int j = 0; j < 8; j++) { float a0 = x0[blk + j] * x0[blk + j]; r0[j] = r0[j] + a0; }
    }
    s0 = ((r0[0] + r0[1]) + (r0[2] + r0[3])) + ((r0[4] + r0[5]) + (r0[6] + r0[7]));
  }

  __syncthreads();   // tt/flags ready

  // constant-addrspace view of the codebook (uniform loads -> s_load_dwordx16)
  const AS4 sf16* wc = (const AS4 sf16*)(unsigned long long)(const void*)w;

  float dmin0 = INFINITY;
  int   k0 = 0;

  for (int c = 0; c < KK; c++) {
    float tc = tt[c];
    // all 64 floats of code c up front; AS4 = invariant, compiler may pipeline
    sf16 A0 = wc[c * 4 + 0];
    sf16 A1 = wc[c * 4 + 1];
    sf16 B0 = wc[c * 4 + 2];
    sf16 B1 = wc[c * 4 + 3];
    float g0 = 0.0f;
    // fmaf chain k-ascending — bit-identical to R1
#pragma unroll
    for (int j = 0; j < 16; j++) g0 = fmaf(x0[j], A0[j], g0);
#pragma unroll
    for (int j = 0; j < 16; j++) g0 = fmaf(x0[16 + j], A1[j], g0);
#pragma unroll
    for (int j = 0; j < 16; j++) g0 = fmaf(x0[32 + j], B0[j], g0);
#pragma unroll
    for (int j = 0; j < 16; j++) g0 = fmaf(x0[48 + j], B1[j], g0);
    float u0 = s0 + tc;                 // fl32(s + t_k), matches np broadcast
    float d0 = fmaf(-2.0f, g0, u0);     // fl32(u - 2g), 2g exact
    if (d0 < dmin0) { dmin0 = d0; k0 = c; }   // strict <: first index on tie
  }

  // epilogue: quantized output (transposed), loss partial, idx
  float ls = 0.0f;
  {
    float* o0 = dout + (size_t)b0 * DD * LL + l0;
    const float4* wr = (const float4*)(w + k0 * DD);
#pragma unroll
    for (int i = 0; i < 16; i++) {
      float4 v = wr[i];
      o0[(size_t)(4*i+0) * LL] = v.x; o0[(size_t)(4*i+1) * LL] = v.y;
      o0[(size_t)(4*i+2) * LL] = v.z; o0[(size_t)(4*i+3) * LL] = v.w;
      float df;
      df = v.x - x0[4*i+0]; ls = fmaf(df, df, ls);
      df = v.y - x0[4*i+1]; ls = fmaf(df, df, ls);
      df = v.z - x0[4*i+2]; ls = fmaf(df, df, ls);
      df = v.w - x0[4*i+3]; ls = fmaf(df, df, ls);
    }
  }
  dout[IDX_OFF + n0] = (float)k0;

  // block loss reduction -> one atomic per block
#pragma unroll
  for (int o = 32; o > 0; o >>= 1) ls += __shfl_down(ls, o);
  if ((tid & 63) == 0) lred[tid >> 6] = ls;
  __syncthreads();
  flags[k0] = 1;
  if (tid == 0) atomicAdd(lacc, (lred[0] + lred[1]) + (lred[2] + lred[3]));
  __syncthreads();
  for (int e = tid; e < KK; e += 256)
    if (flags[e]) atomicOr(&hist[e], 1);

  // last-done block finalizes loss + perplexity
  __threadfence();
  __syncthreads();
  if (tid == 0) {
    int old = __hip_atomic_fetch_add(done, 1, __ATOMIC_ACQ_REL, __HIP_MEMORY_SCOPE_AGENT);
    amLast = (old == (int)gridDim.x - 1);
  }
  __syncthreads();
  if (amLast) {
    __threadfence();
    int v = (__hip_atomic_load(&hist[tid],       __ATOMIC_RELAXED, __HIP_MEMORY_SCOPE_AGENT) != 0)
          + (__hip_atomic_load(&hist[tid + 256], __ATOMIC_RELAXED, __HIP_MEMORY_SCOPE_AGENT) != 0);
#pragma unroll
    for (int o = 32; o > 0; o >>= 1) v += __shfl_down(v, o);
    if ((tid & 63) == 0) ired[tid >> 6] = v;
    __syncthreads();
    if (tid == 0) {
      float m = __hip_atomic_load(lacc, __ATOMIC_RELAXED, __HIP_MEMORY_SCOPE_AGENT)
                / 16777216.0f;
      dout[LOSS_OFF] = m + 0.1f * m;     // q + 0.1*e with q==e numerically
      dout[PERP_OFF] = (float)(ired[0] + ired[1] + ired[2] + ired[3]);
    }
  }
}

extern "C" void kernel_launch(void* const* d_in, const int* in_sizes, int n_in,
                              void* d_out, int out_size, void* d_ws, size_t ws_size,
                              hipStream_t stream) {
  const float* x = (const float*)d_in[0];
  const float* w = (const float*)d_in[1];
  float* dout = (float*)d_out;
  int*   hist = (int*)d_ws;
  float* lacc = (float*)((int*)d_ws + 512);
  int*   done = (int*)d_ws + 513;

  vq_init<<<64, 256, 0, stream>>>(w, hist, lacc, done, dout);
  vq_main<<<NN / 256, 256, 0, stream>>>(x, w, hist, lacc, done, dout);
}

// Round 6
// 496.874 us; speedup vs baseline: 1.0768x; 1.0119x over previous
//
#include <hip/hip_runtime.h>
#include <math.h>

#define BB 32
#define DD 64
#define LL 8192
#define KK 512
#define NN (BB*LL)                 // 262144 rows

#define OUT0_SZ  (BB*DD*LL)        // 16777216
#define LOSS_OFF (OUT0_SZ)
#define PERP_OFF (OUT0_SZ + 1)
#define W_OFF    (OUT0_SZ + 2)
#define IDX_OFF  (W_OFF + KK*DD)

typedef __attribute__((ext_vector_type(16))) float vf16;
#define AS4 __attribute__((address_space(4)))

// x element i of the pinned row (i constant under unroll -> folds)
#define XE(i) ((i) < 16 ? X0[(i)&15] : (i) < 32 ? X1[(i)&15] : (i) < 48 ? X2[(i)&15] : X3[(i)&15])

// ws layout: float tvec[512] | int hist[512] | float lacc | int done
// -----------------------------------------------------------------------------
// init: t_k = ||w_k||^2 (numpy-pairwise fp32 order), zero hist/lacc/done,
// weight passthrough.
__global__ void vq_init(const float* __restrict__ w, float* __restrict__ tvec,
                        int* __restrict__ hist, float* __restrict__ lacc,
                        int* __restrict__ done, float* __restrict__ dout) {
#pragma clang fp contract(off)
  int gid = blockIdx.x * 256 + threadIdx.x;
  if (gid < KK) {
    const float* wr = w + gid * DD;
    float r[8];
#pragma unroll
    for (int j = 0; j < 8; j++) { float v = wr[j]; r[j] = v * v; }
#pragma unroll
    for (int blk = 8; blk < 64; blk += 8) {
#pragma unroll
      for (int j = 0; j < 8; j++) { float v = wr[blk + j]; float a = v * v; r[j] = r[j] + a; }
    }
    tvec[gid] = ((r[0] + r[1]) + (r[2] + r[3])) + ((r[4] + r[5]) + (r[6] + r[7]));
    hist[gid] = 0;
  } else if (gid == KK) {
    *lacc = 0.0f;
  } else if (gid == KK + 1) {
    *done = 0;
  }
  // weight passthrough: dout+W_OFF is 8B-aligned -> float2
  const float2* w2 = (const float2*)w;
  float2* o2 = (float2*)(dout + W_OFF);
  for (int j = gid; j < KK * DD / 2; j += 64 * 256) o2[j] = w2[j];
}

// -----------------------------------------------------------------------------
// main: 1024 blocks x 256 threads, 1 row/thread, 4 waves/EU pinned.
// w + tvec through the scalar pipe (AS4 -> s_load). The empty asm "+v" pin
// inside the loop forces the x row into four 16-VGPR tuples every iteration,
// so the RA cannot park it in AGPRs (R5: accvgpr_read per fma = 2.4x VALU).
__attribute__((amdgpu_waves_per_eu(4, 4)))
__launch_bounds__(256)
__global__ void vq_main(const float* __restrict__ x, const float* __restrict__ w,
                        const float* __restrict__ tvec, int* __restrict__ hist,
                        float* __restrict__ lacc, int* __restrict__ done,
                        float* __restrict__ dout) {
#pragma clang fp contract(off)
  __shared__ unsigned char flags[KK];
  __shared__ float lred[4];
  __shared__ int   ired[4];
  __shared__ int   amLast;

  const int tid = threadIdx.x;
  for (int e = tid; e < KK; e += 256) flags[e] = 0;   // barrier before use: lred sync

  const int n0 = blockIdx.x * 256 + tid;
  const int b0 = n0 >> 13, l0 = n0 & 8191;
  const float* p0 = x + (size_t)b0 * DD * LL + l0;

  vf16 X0, X1, X2, X3;
#pragma unroll
  for (int i = 0; i < 16; i++) {
    X0[i] = p0[(size_t)i * LL];
    X1[i] = p0[(size_t)(i + 16) * LL];
    X2[i] = p0[(size_t)(i + 32) * LL];
    X3[i] = p0[(size_t)(i + 48) * LL];
  }

  // s = ||x||^2 (uniform shift across k; order identical to R1)
  float s0;
  {
    float r0[8];
#pragma unroll
    for (int j = 0; j < 8; j++) r0[j] = XE(j) * XE(j);
#pragma unroll
    for (int blk = 8; blk < 64; blk += 8) {
#pragma unroll
      for (int j = 0; j < 8; j++) { float a0 = XE(blk + j) * XE(blk + j); r0[j] = r0[j] + a0; }
    }
    s0 = ((r0[0] + r0[1]) + (r0[2] + r0[3])) + ((r0[4] + r0[5]) + (r0[6] + r0[7]));
  }

  // constant-addrspace views (uniform loads -> s_load_dwordx16 / s_load_dword)
  const AS4 vf16*  wc  = (const AS4 vf16*)(unsigned long long)(const void*)w;
  const AS4 float* tva = (const AS4 float*)(unsigned long long)(const void*)tvec;

  float dmin0 = INFINITY;
  int   k0 = 0;

  for (int c = 0; c < KK; c++) {
    asm volatile("" : "+v"(X0), "+v"(X1), "+v"(X2), "+v"(X3));  // pin row to VGPRs
    float tc = tva[c];
    vf16 A0 = wc[c * 4 + 0];
    vf16 A1 = wc[c * 4 + 1];
    vf16 B0 = wc[c * 4 + 2];
    vf16 B1 = wc[c * 4 + 3];
    float g0 = 0.0f;
    // fmaf chain k-ascending — bit-identical to R1
#pragma unroll
    for (int j = 0; j < 16; j++) g0 = fmaf(X0[j], A0[j], g0);
#pragma unroll
    for (int j = 0; j < 16; j++) g0 = fmaf(X1[j], A1[j], g0);
#pragma unroll
    for (int j = 0; j < 16; j++) g0 = fmaf(X2[j], B0[j], g0);
#pragma unroll
    for (int j = 0; j < 16; j++) g0 = fmaf(X3[j], B1[j], g0);
    float u0 = s0 + tc;                 // fl32(s + t_k), matches np broadcast
    float d0 = fmaf(-2.0f, g0, u0);     // fl32(u - 2g), 2g exact
    if (d0 < dmin0) { dmin0 = d0; k0 = c; }   // strict <: first index on tie
  }

  // epilogue: quantized output (transposed), loss partial, idx
  float ls = 0.0f;
  {
    float* o0 = dout + (size_t)b0 * DD * LL + l0;
    const float4* wr = (const float4*)(w + k0 * DD);
#pragma unroll
    for (int i = 0; i < 16; i++) {
      float4 v = wr[i];
      o0[(size_t)(4*i+0) * LL] = v.x; o0[(size_t)(4*i+1) * LL] = v.y;
      o0[(size_t)(4*i+2) * LL] = v.z; o0[(size_t)(4*i+3) * LL] = v.w;
      float df;
      df = v.x - XE(4*i+0); ls = fmaf(df, df, ls);
      df = v.y - XE(4*i+1); ls = fmaf(df, df, ls);
      df = v.z - XE(4*i+2); ls = fmaf(df, df, ls);
      df = v.w - XE(4*i+3); ls = fmaf(df, df, ls);
    }
  }
  dout[IDX_OFF + n0] = (float)k0;

  // block loss reduction -> one atomic per block
#pragma unroll
  for (int o = 32; o > 0; o >>= 1) ls += __shfl_down(ls, o);
  if ((tid & 63) == 0) lred[tid >> 6] = ls;
  __syncthreads();                      // orders flags zeroing + lred
  flags[k0] = 1;
  if (tid == 0) atomicAdd(lacc, (lred[0] + lred[1]) + (lred[2] + lred[3]));
  __syncthreads();
  for (int e = tid; e < KK; e += 256)
    if (flags[e]) atomicOr(&hist[e], 1);

  // last-done block finalizes loss + perplexity
  __threadfence();
  __syncthreads();
  if (tid == 0) {
    int old = __hip_atomic_fetch_add(done, 1, __ATOMIC_ACQ_REL, __HIP_MEMORY_SCOPE_AGENT);
    amLast = (old == (int)gridDim.x - 1);
  }
  __syncthreads();
  if (amLast) {
    __threadfence();
    int v = (__hip_atomic_load(&hist[tid],       __ATOMIC_RELAXED, __HIP_MEMORY_SCOPE_AGENT) != 0)
          + (__hip_atomic_load(&hist[tid + 256], __ATOMIC_RELAXED, __HIP_MEMORY_SCOPE_AGENT) != 0);
#pragma unroll
    for (int o = 32; o > 0; o >>= 1) v += __shfl_down(v, o);
    if ((tid & 63) == 0) ired[tid >> 6] = v;
    __syncthreads();
    if (tid == 0) {
      float m = __hip_atomic_load(lacc, __ATOMIC_RELAXED, __HIP_MEMORY_SCOPE_AGENT)
                / 16777216.0f;
      dout[LOSS_OFF] = m + 0.1f * m;     // q + 0.1*e with q==e numerically
      dout[PERP_OFF] = (float)(ired[0] + ired[1] + ired[2] + ired[3]);
    }
  }
}

extern "C" void kernel_launch(void* const* d_in, const int* in_sizes, int n_in,
                              void* d_out, int out_size, void* d_ws, size_t ws_size,
                              hipStream_t stream) {
  const float* x = (const float*)d_in[0];
  const float* w = (const float*)d_in[1];
  float* dout = (float*)d_out;
  float* tvec = (float*)d_ws;
  int*   hist = (int*)d_ws + 512;
  float* lacc = (float*)d_ws + 1024;
  int*   done = (int*)d_ws + 1025;

  vq_init<<<64, 256, 0, stream>>>(w, tvec, hist, lacc, done, dout);
  vq_main<<<NN / 256, 256, 0, stream>>>(x, w, tvec, hist, lacc, done, dout);
}